// Round 4
// baseline (1403.157 us; speedup 1.0000x reference)
//
#include <hip/hip_runtime.h>

#define N_NODES 50000
#define E_EDGES 800000
#define ETOT (E_EDGES + N_NODES)   // self-loops appended
#define IN_CH 128
#define HH 128                     // HEADS*HID
#define HEADS 4
#define HID 32
#define OUT_CH 32
#define NEG 0.2f

// ================= CSR build =================
__global__ void init_deg(int* __restrict__ deg) {
    int i = blockIdx.x * blockDim.x + threadIdx.x;
    if (i < N_NODES) deg[i] = 1;   // self-loop
}

__global__ void count_deg(const int* __restrict__ ei, int* __restrict__ deg) {
    int e = blockIdx.x * blockDim.x + threadIdx.x;
    if (e < E_EDGES) atomicAdd(deg + ei[E_EDGES + e], 1);
}

__device__ __forceinline__ int block_incl_scan(int v, int t) {
    for (int off = 1; off < 64; off <<= 1) {
        int n = __shfl_up(v, off, 64);
        if ((t & 63) >= off) v += n;
    }
    __shared__ int wsum[4];
    if ((t & 63) == 63) wsum[t >> 6] = v;
    __syncthreads();
    int w = t >> 6;
    if (w > 0) {
        int add = 0;
        for (int k = 0; k < w; ++k) add += wsum[k];
        v += add;
    }
    __syncthreads();
    return v;
}

#define NCHUNK ((N_NODES + 255) / 256)   // 196

__global__ void scan_s1(const int* __restrict__ deg, int* __restrict__ rowptr,
                        int* __restrict__ partials) {
    int t = threadIdx.x;
    int i = blockIdx.x * 256 + t;
    int v = (i < N_NODES) ? deg[i] : 0;
    int s = block_incl_scan(v, t);
    if (i < N_NODES) rowptr[i + 1] = s;
    if (t == 255) partials[blockIdx.x] = s;
}

__global__ void scan_s2(int* __restrict__ partials) {
    int t = threadIdx.x;
    int v = (t < NCHUNK) ? partials[t] : 0;
    int s = block_incl_scan(v, t);
    if (t < NCHUNK) partials[t] = s;
}

__global__ void scan_s3(int* __restrict__ rowptr, const int* __restrict__ partials) {
    int i = blockIdx.x * blockDim.x + threadIdx.x;
    if (i == 0) rowptr[0] = 0;
    if (i < N_NODES) {
        int c = i >> 8;
        if (c > 0) rowptr[i + 1] += partials[c - 1];
    }
}

__global__ void init_cursor(const int* __restrict__ rowptr, int* __restrict__ cursor) {
    int i = blockIdx.x * blockDim.x + threadIdx.x;
    if (i < N_NODES) cursor[i] = rowptr[i];
}

__global__ void fill_csr(const int* __restrict__ ei, int* __restrict__ cursor,
                         int* __restrict__ csr_src) {
    int e = blockIdx.x * blockDim.x + threadIdx.x;
    if (e >= ETOT) return;
    int s, d;
    if (e < E_EDGES) { s = ei[e]; d = ei[E_EDGES + e]; }
    else { s = e - E_EDGES; d = s; }
    int pos = atomicAdd(cursor + d, 1);
    csr_src[pos] = s;
}

// ================= layer-1 GEMM: xw1 = x @ W1 (register-blocked) =================
#define TILE_ROWS 64
#define WPAD (IN_CH + 4)   // pad 4 floats: keeps 16B alignment, spreads banks

__global__ __launch_bounds__(512, 1) void gemm1_kernel(const float* __restrict__ x,
                                                       const float* __restrict__ W1,
                                                       float* __restrict__ xw) {
    __shared__ float Wl[HH * WPAD];          // transposed W: Wl[j][k], 66 KiB
    __shared__ float Xs[TILE_ROWS * IN_CH];  // 32 KiB
    int t = threadIdx.x;
    // stage W transposed: Wl[j][k] = W1[k*HH + j]
    for (int i = t; i < IN_CH * HH; i += 512) {
        int k = i >> 7, j = i & 127;
        Wl[j * WPAD + k] = W1[i];
    }
    // stage X tile (coalesced float4)
    int row0 = blockIdx.x * TILE_ROWS;
    for (int i = t; i < TILE_ROWS * (IN_CH / 4); i += 512) {
        int rr = i >> 5, c4 = i & 31;
        int row = row0 + rr;
        float4 v = make_float4(0.f, 0.f, 0.f, 0.f);
        if (row < N_NODES) v = ((const float4*)(x + (size_t)row * IN_CH))[c4];
        ((float4*)(Xs + rr * IN_CH))[c4] = v;
    }
    __syncthreads();

    int tr = t >> 5, tc = t & 31;   // rows tr+{0,16,32,48}, cols tc+{0,32,64,96}
    float acc[4][4] = {};
#pragma unroll
    for (int k = 0; k < IN_CH; k += 4) {
        float4 xv0 = *(const float4*)&Xs[(tr     ) * IN_CH + k];
        float4 xv1 = *(const float4*)&Xs[(tr + 16) * IN_CH + k];
        float4 xv2 = *(const float4*)&Xs[(tr + 32) * IN_CH + k];
        float4 xv3 = *(const float4*)&Xs[(tr + 48) * IN_CH + k];
        float4 wv0 = *(const float4*)&Wl[(tc     ) * WPAD + k];
        float4 wv1 = *(const float4*)&Wl[(tc + 32) * WPAD + k];
        float4 wv2 = *(const float4*)&Wl[(tc + 64) * WPAD + k];
        float4 wv3 = *(const float4*)&Wl[(tc + 96) * WPAD + k];
#define DO(i, g, XV, WV)                                   \
        acc[i][g] = fmaf(XV.x, WV.x, acc[i][g]);           \
        acc[i][g] = fmaf(XV.y, WV.y, acc[i][g]);           \
        acc[i][g] = fmaf(XV.z, WV.z, acc[i][g]);           \
        acc[i][g] = fmaf(XV.w, WV.w, acc[i][g]);
        DO(0,0,xv0,wv0) DO(0,1,xv0,wv1) DO(0,2,xv0,wv2) DO(0,3,xv0,wv3)
        DO(1,0,xv1,wv0) DO(1,1,xv1,wv1) DO(1,2,xv1,wv2) DO(1,3,xv1,wv3)
        DO(2,0,xv2,wv0) DO(2,1,xv2,wv1) DO(2,2,xv2,wv2) DO(2,3,xv2,wv3)
        DO(3,0,xv3,wv0) DO(3,1,xv3,wv1) DO(3,2,xv3,wv2) DO(3,3,xv3,wv3)
#undef DO
    }
#pragma unroll
    for (int i = 0; i < 4; ++i) {
        int row = row0 + tr + 16 * i;
        if (row < N_NODES) {
            float* o = xw + (size_t)row * HH + tc;
            o[0]  = acc[i][0];
            o[32] = acc[i][1];
            o[64] = acc[i][2];
            o[96] = acc[i][3];
        }
    }
}

// ================= attention dots: a1s/a1d from xw1 =================
__global__ void att_dots(const float* __restrict__ xw,
                         const float* __restrict__ att_s,
                         const float* __restrict__ att_d,
                         float* __restrict__ a1s, float* __restrict__ a1d) {
    int t = threadIdx.x;
    int row = blockIdx.x * 4 + (t >> 6);
    if (row >= N_NODES) return;
    int l = t & 63;
    const float* xr = xw + (size_t)row * HH;
    float x1 = xr[l], x2 = xr[l + 64];
    float p1s = x1 * att_s[l],      p1d = x1 * att_d[l];
    float p2s = x2 * att_s[l + 64], p2d = x2 * att_d[l + 64];
    for (int off = 16; off; off >>= 1) {
        p1s += __shfl_xor(p1s, off, 32);
        p1d += __shfl_xor(p1d, off, 32);
        p2s += __shfl_xor(p2s, off, 32);
        p2d += __shfl_xor(p2d, off, 32);
    }
    // lanes 0..31 hold heads {0,2}; lanes 32..63 hold heads {1,3}
    if (l == 0) {
        a1s[row * 4 + 0] = p1s; a1s[row * 4 + 2] = p2s;
        a1d[row * 4 + 0] = p1d; a1d[row * 4 + 2] = p2d;
    } else if (l == 32) {
        a1s[row * 4 + 1] = p1s; a1s[row * 4 + 3] = p2s;
        a1d[row * 4 + 1] = p1d; a1d[row * 4 + 3] = p2d;
    }
}

// ================= layer-1 softmax denominators (per-node wave) =================
__global__ void denom1_csr(const int* __restrict__ rowptr, const int* __restrict__ csr_src,
                           const float* __restrict__ a1s, const float* __restrict__ a1d,
                           float* __restrict__ rden) {
    int t = threadIdx.x;
    int d = blockIdx.x * 4 + (t >> 6);
    if (d >= N_NODES) return;
    int l = t & 63;
    int h = l & 3, el = l >> 2;          // 16 edge slots x 4 heads
    float ad = a1d[d * 4 + h];
    int p0 = rowptr[d], p1 = rowptr[d + 1];
    float sum = 0.f;
    for (int p = p0 + el; p < p1; p += 16) {
        int s = csr_src[p];
        float v = a1s[s * 4 + h] + ad;
        v = v > 0.f ? v : NEG * v;
        sum += __expf(v);
    }
    for (int off = 4; off < 64; off <<= 1) sum += __shfl_xor(sum, off, 64);
    if (l < 4) rden[d * 4 + l] = 1.f / (sum + 1e-16f);
}

// ================= layer-1 gather-aggregate =================
__global__ void gather1(const int* __restrict__ rowptr, const int* __restrict__ csr_src,
                        const float* __restrict__ a1s, const float* __restrict__ a1d,
                        const float* __restrict__ rden,
                        const float* __restrict__ xw, float* __restrict__ agg) {
    int t = threadIdx.x;
    int d = blockIdx.x * 2 + (t >> 7);
    if (d >= N_NODES) return;
    int j = t & 127, h = j >> 5;
    float ad = a1d[d * 4 + h];
    float rd = rden[d * 4 + h];
    int p0 = rowptr[d], p1 = rowptr[d + 1];
    float acc = 0.f;
    for (int p = p0; p < p1; ++p) {
        int s = csr_src[p];
        float v = a1s[s * 4 + h] + ad;
        v = v > 0.f ? v : NEG * v;
        float w = __expf(v);
        acc = fmaf(w, xw[(size_t)s * HH + j], acc);
    }
    agg[(size_t)d * HH + j] = acc * rd;
}

// ====== layer-2 GEMM: h = elu(agg+b1); hw2 = h @ W2, + attention dots ======
__global__ void gemm2_kernel(const float* __restrict__ agg1,
                             const float* __restrict__ b1,
                             const float* __restrict__ W2,
                             const float* __restrict__ att_s,
                             const float* __restrict__ att_d,
                             float* __restrict__ hw2,
                             float* __restrict__ a2s,
                             float* __restrict__ a2d) {
    __shared__ float Wl[HH * OUT_CH];  // 16 KiB
    __shared__ float hs[8][HH];        // 4 KiB
    int t = threadIdx.x;
    for (int i = t; i < HH * OUT_CH; i += 256) Wl[i] = W2[i];
    __syncthreads();
    int nChunks = (N_NODES + 7) / 8;
    for (int ch = blockIdx.x; ch < nChunks; ch += gridDim.x) {
        int row0 = ch * 8;
        __syncthreads();
        for (int i = t; i < 8 * HH; i += 256) {
            int rr = i >> 7, jj = i & 127;
            int row = row0 + rr;
            if (row < N_NODES) {
                float v = agg1[(size_t)row * HH + jj] + b1[jj];
                hs[rr][jj] = v > 0.f ? v : (__expf(v) - 1.f);   // ELU
            }
        }
        __syncthreads();
        int r = t >> 5, o = t & 31;
        int row = row0 + r;
        if (row < N_NODES) {
            float acc = 0.f;
#pragma unroll 4
            for (int jj = 0; jj < HH; ++jj) acc = fmaf(hs[r][jj], Wl[jj * OUT_CH + o], acc);
            hw2[(size_t)row * OUT_CH + o] = acc;
            float ps = acc * att_s[o], pd = acc * att_d[o];
            for (int off = 16; off; off >>= 1) {
                ps += __shfl_down(ps, off, 32);
                pd += __shfl_down(pd, off, 32);
            }
            if (o == 0) { a2s[row] = ps; a2d[row] = pd; }
        }
    }
}

// ================= layer-2 denominators =================
__global__ void denom2_csr(const int* __restrict__ rowptr, const int* __restrict__ csr_src,
                           const float* __restrict__ a2s, const float* __restrict__ a2d,
                           float* __restrict__ rden2) {
    int t = threadIdx.x;
    int d = blockIdx.x * 4 + (t >> 6);
    if (d >= N_NODES) return;
    int l = t & 63;
    float ad = a2d[d];
    int p0 = rowptr[d], p1 = rowptr[d + 1];
    float sum = 0.f;
    for (int p = p0 + l; p < p1; p += 64) {
        int s = csr_src[p];
        float v = a2s[s] + ad;
        v = v > 0.f ? v : NEG * v;
        sum += __expf(v);
    }
    for (int off = 32; off; off >>= 1) sum += __shfl_xor(sum, off, 64);
    if (l == 0) rden2[d] = 1.f / (sum + 1e-16f);
}

// ================= layer-2 gather-aggregate (writes final out) =================
__global__ void gather2(const int* __restrict__ rowptr, const int* __restrict__ csr_src,
                        const float* __restrict__ a2s, const float* __restrict__ a2d,
                        const float* __restrict__ rden2,
                        const float* __restrict__ hw2, const float* __restrict__ b2,
                        float* __restrict__ out) {
    int t = threadIdx.x;
    int d = blockIdx.x * 4 + (t >> 6);
    if (d >= N_NODES) return;
    int l = t & 63;
    int o = l & 31, el = l >> 5;
    float ad = a2d[d];
    int p0 = rowptr[d], p1 = rowptr[d + 1];
    float acc = 0.f;
    for (int p = p0 + el; p < p1; p += 2) {
        int s = csr_src[p];
        float v = a2s[s] + ad;
        v = v > 0.f ? v : NEG * v;
        acc = fmaf(__expf(v), hw2[(size_t)s * OUT_CH + o], acc);
    }
    acc += __shfl_down(acc, 32, 64);
    if (el == 0) out[(size_t)d * OUT_CH + o] = acc * rden2[d] + b2[o];
}

extern "C" void kernel_launch(void* const* d_in, const int* in_sizes, int n_in,
                              void* d_out, int out_size, void* d_ws, size_t ws_size,
                              hipStream_t stream) {
    const float* x   = (const float*)d_in[0];
    const int*   ei  = (const int*)d_in[1];     // int32 (JAX x64 off)
    const float* W1  = (const float*)d_in[2];
    const float* as1 = (const float*)d_in[3];
    const float* ad1 = (const float*)d_in[4];
    const float* b1  = (const float*)d_in[5];
    const float* W2  = (const float*)d_in[6];
    const float* as2 = (const float*)d_in[7];
    const float* ad2 = (const float*)d_in[8];
    const float* b2  = (const float*)d_in[9];
    float* out = (float*)d_out;
    float* ws  = (float*)d_ws;

    // workspace layout (floats); peak 14.36M floats = 57.4 MB
    float* xw1    = ws;                        // 6,400,000 ; hw2 reuses
    float* hw2    = ws;
    float* agg1   = ws + 6400000;              // 6,400,000
    float* a1s    = ws + 12800000;             //   200,000 ; a2s reuses
    float* a1d    = ws + 13000000;             //   200,000 ; a2d reuses
    float* a2s    = a1s;
    float* a2d    = a1d;
    float* rden1  = ws + 13200000;             //   200,000 ; rden2 reuses
    float* rden2  = rden1;
    int*   deg    = (int*)(ws + 13400000);     //    50,000 (also cursor)
    int*   rowptr = (int*)(ws + 13450000);     //    50,016
    int*   parts  = (int*)(ws + 13500016);     //       256
    int*   csr_src= (int*)(ws + 13500272);     //   850,000  -> end 14,350,272

    // ---- CSR build (graph-only) ----
    init_deg   <<<(N_NODES + 255) / 256, 256, 0, stream>>>(deg);
    count_deg  <<<(E_EDGES + 255) / 256, 256, 0, stream>>>(ei, deg);
    scan_s1    <<<NCHUNK, 256, 0, stream>>>(deg, rowptr, parts);
    scan_s2    <<<1, 256, 0, stream>>>(parts);
    scan_s3    <<<(N_NODES + 255) / 256, 256, 0, stream>>>(rowptr, parts);
    init_cursor<<<(N_NODES + 255) / 256, 256, 0, stream>>>(rowptr, deg);
    fill_csr   <<<(ETOT + 255) / 256, 256, 0, stream>>>(ei, deg, csr_src);

    // ---- layer 1 ----
    gemm1_kernel<<<(N_NODES + TILE_ROWS - 1) / TILE_ROWS, 512, 0, stream>>>(x, W1, xw1);
    att_dots   <<<(N_NODES + 3) / 4, 256, 0, stream>>>(xw1, as1, ad1, a1s, a1d);
    denom1_csr <<<(N_NODES + 3) / 4, 256, 0, stream>>>(rowptr, csr_src, a1s, a1d, rden1);
    gather1    <<<(N_NODES + 1) / 2, 256, 0, stream>>>(rowptr, csr_src, a1s, a1d, rden1, xw1, agg1);

    // ---- layer 2 ----
    gemm2_kernel<<<2048, 256, 0, stream>>>(agg1, b1, W2, as2, ad2, hw2, a2s, a2d);
    denom2_csr <<<(N_NODES + 3) / 4, 256, 0, stream>>>(rowptr, csr_src, a2s, a2d, rden2);
    gather2    <<<(N_NODES + 3) / 4, 256, 0, stream>>>(rowptr, csr_src, a2s, a2d, rden2, hw2, b2, out);
}

// Round 5
// 416.513 us; speedup vs baseline: 3.3688x; 3.3688x over previous
//
#include <hip/hip_runtime.h>

#define N_NODES 50000
#define E_EDGES 800000
#define ETOT (E_EDGES + N_NODES)   // self-loops appended
#define IN_CH 128
#define HH 128                     // HEADS*HID
#define HEADS 4
#define HID 32
#define OUT_CH 32
#define NEG 0.2f

// ================= CSR build =================
__global__ void init_deg(int* __restrict__ deg) {
    int i = blockIdx.x * blockDim.x + threadIdx.x;
    if (i < N_NODES) deg[i] = 1;   // self-loop
}

__global__ void count_deg(const int* __restrict__ ei, int* __restrict__ deg) {
    int e = blockIdx.x * blockDim.x + threadIdx.x;
    if (e < E_EDGES) atomicAdd(deg + ei[E_EDGES + e], 1);
}

__device__ __forceinline__ int block_incl_scan(int v, int t) {
    for (int off = 1; off < 64; off <<= 1) {
        int n = __shfl_up(v, off, 64);
        if ((t & 63) >= off) v += n;
    }
    __shared__ int wsum[4];
    if ((t & 63) == 63) wsum[t >> 6] = v;
    __syncthreads();
    int w = t >> 6;
    if (w > 0) {
        int add = 0;
        for (int k = 0; k < w; ++k) add += wsum[k];
        v += add;
    }
    __syncthreads();
    return v;
}

#define NCHUNK ((N_NODES + 255) / 256)   // 196

__global__ void scan_s1(const int* __restrict__ deg, int* __restrict__ rowptr,
                        int* __restrict__ partials) {
    int t = threadIdx.x;
    int i = blockIdx.x * 256 + t;
    int v = (i < N_NODES) ? deg[i] : 0;
    int s = block_incl_scan(v, t);
    if (i < N_NODES) rowptr[i + 1] = s;
    if (t == 255) partials[blockIdx.x] = s;
}

__global__ void scan_s2(int* __restrict__ partials) {
    int t = threadIdx.x;
    int v = (t < NCHUNK) ? partials[t] : 0;
    int s = block_incl_scan(v, t);
    if (t < NCHUNK) partials[t] = s;
}

__global__ void scan_s3(int* __restrict__ rowptr, const int* __restrict__ partials) {
    int i = blockIdx.x * blockDim.x + threadIdx.x;
    if (i == 0) rowptr[0] = 0;
    if (i < N_NODES) {
        int c = i >> 8;
        if (c > 0) rowptr[i + 1] += partials[c - 1];
    }
}

__global__ void init_cursor(const int* __restrict__ rowptr, int* __restrict__ cursor) {
    int i = blockIdx.x * blockDim.x + threadIdx.x;
    if (i < N_NODES) cursor[i] = rowptr[i];
}

__global__ void fill_csr(const int* __restrict__ ei, int* __restrict__ cursor,
                         int* __restrict__ csr_src) {
    int e = blockIdx.x * blockDim.x + threadIdx.x;
    if (e >= ETOT) return;
    int s, d;
    if (e < E_EDGES) { s = ei[e]; d = ei[E_EDGES + e]; }
    else { s = e - E_EDGES; d = s; }
    int pos = atomicAdd(cursor + d, 1);
    csr_src[pos] = s;
}

// ============ layer-1 GEMM: xw1 = x @ W1 (128x128 tile, BK=32) ============
// 256 threads, 8x8 micro-tile per thread. LDS 33KB, ~110 VGPR -> no spill.
#define XP 132   // padded LDS row stride (floats): breaks stride-128 banks, keeps 16B align

__global__ __launch_bounds__(256, 2) void gemm1_kernel(const float* __restrict__ x,
                                                       const float* __restrict__ W1,
                                                       float* __restrict__ xw) {
    __shared__ float Xs[32][XP];   // Xs[kk][row]  (transposed tile)
    __shared__ float Ws[32][XP];   // Ws[kk][col]
    int t = threadIdx.x;
    int tx = t & 15, ty = t >> 4;       // 16 x 16 thread grid
    int row0 = blockIdx.x * 128;
    float acc[8][8] = {};

    for (int k0 = 0; k0 < IN_CH; k0 += 32) {
        // stage W chunk [k0..k0+31][0..127]  (coalesced float4, direct)
#pragma unroll
        for (int p = 0; p < 4; ++p) {
            int idx = t + p * 256;        // 0..1023
            int kk = idx >> 5, c4 = idx & 31;
            float4 v = *(const float4*)&W1[(size_t)(k0 + kk) * HH + c4 * 4];
            *(float4*)&Ws[kk][c4 * 4] = v;
        }
        // stage X chunk transposed: Xs[kk][row]
#pragma unroll
        for (int p = 0; p < 4; ++p) {
            int idx = t + p * 256;        // 0..1023
            int rr = idx >> 3, c4 = idx & 7;
            int row = row0 + rr;
            float4 v = make_float4(0.f, 0.f, 0.f, 0.f);
            if (row < N_NODES) v = *(const float4*)&x[(size_t)row * IN_CH + k0 + c4 * 4];
            Xs[c4 * 4 + 0][rr] = v.x;
            Xs[c4 * 4 + 1][rr] = v.y;
            Xs[c4 * 4 + 2][rr] = v.z;
            Xs[c4 * 4 + 3][rr] = v.w;
        }
        __syncthreads();
#pragma unroll 8
        for (int kk = 0; kk < 32; ++kk) {
            float4 xa0 = *(const float4*)&Xs[kk][ty * 4];
            float4 xa1 = *(const float4*)&Xs[kk][ty * 4 + 64];
            float4 wb0 = *(const float4*)&Ws[kk][tx * 4];
            float4 wb1 = *(const float4*)&Ws[kk][tx * 4 + 64];
            float xa[8] = {xa0.x, xa0.y, xa0.z, xa0.w, xa1.x, xa1.y, xa1.z, xa1.w};
            float wb[8] = {wb0.x, wb0.y, wb0.z, wb0.w, wb1.x, wb1.y, wb1.z, wb1.w};
#pragma unroll
            for (int i = 0; i < 8; ++i)
#pragma unroll
                for (int j = 0; j < 8; ++j)
                    acc[i][j] = fmaf(xa[i], wb[j], acc[i][j]);
        }
        __syncthreads();
    }

#pragma unroll
    for (int i = 0; i < 8; ++i) {
        int row = row0 + ty * 4 + (i < 4 ? i : 60 + i);   // +64 for upper half
        if (row < N_NODES) {
            float4 v0 = make_float4(acc[i][0], acc[i][1], acc[i][2], acc[i][3]);
            float4 v1 = make_float4(acc[i][4], acc[i][5], acc[i][6], acc[i][7]);
            *(float4*)&xw[(size_t)row * HH + tx * 4]      = v0;
            *(float4*)&xw[(size_t)row * HH + tx * 4 + 64] = v1;
        }
    }
}

// ================= attention dots: a1s/a1d from xw1 =================
__global__ void att_dots(const float* __restrict__ xw,
                         const float* __restrict__ att_s,
                         const float* __restrict__ att_d,
                         float* __restrict__ a1s, float* __restrict__ a1d) {
    int t = threadIdx.x;
    int row = blockIdx.x * 4 + (t >> 6);
    if (row >= N_NODES) return;
    int l = t & 63;
    const float* xr = xw + (size_t)row * HH;
    float x1 = xr[l], x2 = xr[l + 64];
    float p1s = x1 * att_s[l],      p1d = x1 * att_d[l];
    float p2s = x2 * att_s[l + 64], p2d = x2 * att_d[l + 64];
    for (int off = 16; off; off >>= 1) {
        p1s += __shfl_xor(p1s, off, 32);
        p1d += __shfl_xor(p1d, off, 32);
        p2s += __shfl_xor(p2s, off, 32);
        p2d += __shfl_xor(p2d, off, 32);
    }
    if (l == 0) {
        a1s[row * 4 + 0] = p1s; a1s[row * 4 + 2] = p2s;
        a1d[row * 4 + 0] = p1d; a1d[row * 4 + 2] = p2d;
    } else if (l == 32) {
        a1s[row * 4 + 1] = p1s; a1s[row * 4 + 3] = p2s;
        a1d[row * 4 + 1] = p1d; a1d[row * 4 + 3] = p2d;
    }
}

// ================= layer-1 softmax denominators (per-node wave) =================
__global__ void denom1_csr(const int* __restrict__ rowptr, const int* __restrict__ csr_src,
                           const float* __restrict__ a1s, const float* __restrict__ a1d,
                           float* __restrict__ rden) {
    int t = threadIdx.x;
    int d = blockIdx.x * 4 + (t >> 6);
    if (d >= N_NODES) return;
    int l = t & 63;
    int h = l & 3, el = l >> 2;          // 16 edge slots x 4 heads
    float ad = a1d[d * 4 + h];
    int p0 = rowptr[d], p1 = rowptr[d + 1];
    float sum = 0.f;
    for (int p = p0 + el; p < p1; p += 16) {
        int s = csr_src[p];
        float v = a1s[s * 4 + h] + ad;
        v = v > 0.f ? v : NEG * v;
        sum += __expf(v);
    }
    for (int off = 4; off < 64; off <<= 1) sum += __shfl_xor(sum, off, 64);
    if (l < 4) rden[d * 4 + l] = 1.f / (sum + 1e-16f);
}

// ================= layer-1 gather-aggregate =================
__global__ void gather1(const int* __restrict__ rowptr, const int* __restrict__ csr_src,
                        const float* __restrict__ a1s, const float* __restrict__ a1d,
                        const float* __restrict__ rden,
                        const float* __restrict__ xw, float* __restrict__ agg) {
    int t = threadIdx.x;
    int d = blockIdx.x * 2 + (t >> 7);
    if (d >= N_NODES) return;
    int j = t & 127, h = j >> 5;
    float ad = a1d[d * 4 + h];
    float rd = rden[d * 4 + h];
    int p0 = rowptr[d], p1 = rowptr[d + 1];
    float acc = 0.f;
    for (int p = p0; p < p1; ++p) {
        int s = csr_src[p];
        float v = a1s[s * 4 + h] + ad;
        v = v > 0.f ? v : NEG * v;
        float w = __expf(v);
        acc = fmaf(w, xw[(size_t)s * HH + j], acc);
    }
    agg[(size_t)d * HH + j] = acc * rd;
}

// ====== layer-2 GEMM: h = elu(agg+b1); hw2 = h @ W2, + attention dots ======
__global__ void gemm2_kernel(const float* __restrict__ agg1,
                             const float* __restrict__ b1,
                             const float* __restrict__ W2,
                             const float* __restrict__ att_s,
                             const float* __restrict__ att_d,
                             float* __restrict__ hw2,
                             float* __restrict__ a2s,
                             float* __restrict__ a2d) {
    __shared__ float Wl[HH * OUT_CH];  // 16 KiB
    __shared__ float hs[8][HH];        // 4 KiB
    int t = threadIdx.x;
    for (int i = t; i < HH * OUT_CH; i += 256) Wl[i] = W2[i];
    __syncthreads();
    int nChunks = (N_NODES + 7) / 8;
    for (int ch = blockIdx.x; ch < nChunks; ch += gridDim.x) {
        int row0 = ch * 8;
        __syncthreads();
        for (int i = t; i < 8 * HH; i += 256) {
            int rr = i >> 7, jj = i & 127;
            int row = row0 + rr;
            if (row < N_NODES) {
                float v = agg1[(size_t)row * HH + jj] + b1[jj];
                hs[rr][jj] = v > 0.f ? v : (__expf(v) - 1.f);   // ELU
            }
        }
        __syncthreads();
        int r = t >> 5, o = t & 31;
        int row = row0 + r;
        if (row < N_NODES) {
            float acc = 0.f;
#pragma unroll 4
            for (int jj = 0; jj < HH; ++jj) acc = fmaf(hs[r][jj], Wl[jj * OUT_CH + o], acc);
            hw2[(size_t)row * OUT_CH + o] = acc;
            float ps = acc * att_s[o], pd = acc * att_d[o];
            for (int off = 16; off; off >>= 1) {
                ps += __shfl_down(ps, off, 32);
                pd += __shfl_down(pd, off, 32);
            }
            if (o == 0) { a2s[row] = ps; a2d[row] = pd; }
        }
    }
}

// ================= layer-2 denominators =================
__global__ void denom2_csr(const int* __restrict__ rowptr, const int* __restrict__ csr_src,
                           const float* __restrict__ a2s, const float* __restrict__ a2d,
                           float* __restrict__ rden2) {
    int t = threadIdx.x;
    int d = blockIdx.x * 4 + (t >> 6);
    if (d >= N_NODES) return;
    int l = t & 63;
    float ad = a2d[d];
    int p0 = rowptr[d], p1 = rowptr[d + 1];
    float sum = 0.f;
    for (int p = p0 + l; p < p1; p += 64) {
        int s = csr_src[p];
        float v = a2s[s] + ad;
        v = v > 0.f ? v : NEG * v;
        sum += __expf(v);
    }
    for (int off = 32; off; off >>= 1) sum += __shfl_xor(sum, off, 64);
    if (l == 0) rden2[d] = 1.f / (sum + 1e-16f);
}

// ================= layer-2 gather-aggregate (writes final out) =================
__global__ void gather2(const int* __restrict__ rowptr, const int* __restrict__ csr_src,
                        const float* __restrict__ a2s, const float* __restrict__ a2d,
                        const float* __restrict__ rden2,
                        const float* __restrict__ hw2, const float* __restrict__ b2,
                        float* __restrict__ out) {
    int t = threadIdx.x;
    int d = blockIdx.x * 4 + (t >> 6);
    if (d >= N_NODES) return;
    int l = t & 63;
    int o = l & 31, el = l >> 5;
    float ad = a2d[d];
    int p0 = rowptr[d], p1 = rowptr[d + 1];
    float acc = 0.f;
    for (int p = p0 + el; p < p1; p += 2) {
        int s = csr_src[p];
        float v = a2s[s] + ad;
        v = v > 0.f ? v : NEG * v;
        acc = fmaf(__expf(v), hw2[(size_t)s * OUT_CH + o], acc);
    }
    acc += __shfl_down(acc, 32, 64);
    if (el == 0) out[(size_t)d * OUT_CH + o] = acc * rden2[d] + b2[o];
}

extern "C" void kernel_launch(void* const* d_in, const int* in_sizes, int n_in,
                              void* d_out, int out_size, void* d_ws, size_t ws_size,
                              hipStream_t stream) {
    const float* x   = (const float*)d_in[0];
    const int*   ei  = (const int*)d_in[1];     // int32 (JAX x64 off)
    const float* W1  = (const float*)d_in[2];
    const float* as1 = (const float*)d_in[3];
    const float* ad1 = (const float*)d_in[4];
    const float* b1  = (const float*)d_in[5];
    const float* W2  = (const float*)d_in[6];
    const float* as2 = (const float*)d_in[7];
    const float* ad2 = (const float*)d_in[8];
    const float* b2  = (const float*)d_in[9];
    float* out = (float*)d_out;
    float* ws  = (float*)d_ws;

    // workspace layout (floats); peak 14.36M floats = 57.4 MB
    float* xw1    = ws;                        // 6,400,000 ; hw2 reuses
    float* hw2    = ws;
    float* agg1   = ws + 6400000;              // 6,400,000
    float* a1s    = ws + 12800000;             //   200,000 ; a2s reuses
    float* a1d    = ws + 13000000;             //   200,000 ; a2d reuses
    float* a2s    = a1s;
    float* a2d    = a1d;
    float* rden1  = ws + 13200000;             //   200,000 ; rden2 reuses
    float* rden2  = rden1;
    int*   deg    = (int*)(ws + 13400000);     //    50,000 (also cursor)
    int*   rowptr = (int*)(ws + 13450000);     //    50,016
    int*   parts  = (int*)(ws + 13500016);     //       256
    int*   csr_src= (int*)(ws + 13500272);     //   850,000  -> end 14,350,272

    // ---- CSR build (graph-only) ----
    init_deg   <<<(N_NODES + 255) / 256, 256, 0, stream>>>(deg);
    count_deg  <<<(E_EDGES + 255) / 256, 256, 0, stream>>>(ei, deg);
    scan_s1    <<<NCHUNK, 256, 0, stream>>>(deg, rowptr, parts);
    scan_s2    <<<1, 256, 0, stream>>>(parts);
    scan_s3    <<<(N_NODES + 255) / 256, 256, 0, stream>>>(rowptr, parts);
    init_cursor<<<(N_NODES + 255) / 256, 256, 0, stream>>>(rowptr, deg);
    fill_csr   <<<(ETOT + 255) / 256, 256, 0, stream>>>(ei, deg, csr_src);

    // ---- layer 1 ----
    gemm1_kernel<<<(N_NODES + 127) / 128, 256, 0, stream>>>(x, W1, xw1);
    att_dots   <<<(N_NODES + 3) / 4, 256, 0, stream>>>(xw1, as1, ad1, a1s, a1d);
    denom1_csr <<<(N_NODES + 3) / 4, 256, 0, stream>>>(rowptr, csr_src, a1s, a1d, rden1);
    gather1    <<<(N_NODES + 1) / 2, 256, 0, stream>>>(rowptr, csr_src, a1s, a1d, rden1, xw1, agg1);

    // ---- layer 2 ----
    gemm2_kernel<<<2048, 256, 0, stream>>>(agg1, b1, W2, as2, ad2, hw2, a2s, a2d);
    denom2_csr <<<(N_NODES + 3) / 4, 256, 0, stream>>>(rowptr, csr_src, a2s, a2d, rden2);
    gather2    <<<(N_NODES + 3) / 4, 256, 0, stream>>>(rowptr, csr_src, a2s, a2d, rden2, hw2, b2, out);
}

// Round 6
// 261.331 us; speedup vs baseline: 5.3693x; 1.5938x over previous
//
#include <hip/hip_runtime.h>
#include <hip/hip_fp16.h>

#define N_NODES 50000
#define E_EDGES 800000
#define ETOT (E_EDGES + N_NODES)   // self-loops appended
#define IN_CH 128
#define HH 128                     // HEADS*HID
#define HEADS 4
#define HID 32
#define OUT_CH 32
#define NEG 0.2f

// ================= CSR build =================
__global__ void init_deg(int* __restrict__ deg) {
    int i = blockIdx.x * blockDim.x + threadIdx.x;
    if (i < N_NODES) deg[i] = 1;   // self-loop
}

__global__ void count_deg(const int* __restrict__ ei, int* __restrict__ deg) {
    int e = blockIdx.x * blockDim.x + threadIdx.x;
    if (e < E_EDGES) atomicAdd(deg + ei[E_EDGES + e], 1);
}

__device__ __forceinline__ int block_incl_scan(int v, int t) {
    for (int off = 1; off < 64; off <<= 1) {
        int n = __shfl_up(v, off, 64);
        if ((t & 63) >= off) v += n;
    }
    __shared__ int wsum[4];
    if ((t & 63) == 63) wsum[t >> 6] = v;
    __syncthreads();
    int w = t >> 6;
    if (w > 0) {
        int add = 0;
        for (int k = 0; k < w; ++k) add += wsum[k];
        v += add;
    }
    __syncthreads();
    return v;
}

#define NCHUNK ((N_NODES + 255) / 256)   // 196

__global__ void scan_s1(const int* __restrict__ deg, int* __restrict__ rowptr,
                        int* __restrict__ partials) {
    int t = threadIdx.x;
    int i = blockIdx.x * 256 + t;
    int v = (i < N_NODES) ? deg[i] : 0;
    int s = block_incl_scan(v, t);
    if (i < N_NODES) rowptr[i + 1] = s;
    if (t == 255) partials[blockIdx.x] = s;
}

__global__ void scan_s2(int* __restrict__ partials) {
    int t = threadIdx.x;
    int v = (t < NCHUNK) ? partials[t] : 0;
    int s = block_incl_scan(v, t);
    if (t < NCHUNK) partials[t] = s;
}

__global__ void scan_s3(int* __restrict__ rowptr, const int* __restrict__ partials) {
    int i = blockIdx.x * blockDim.x + threadIdx.x;
    if (i == 0) rowptr[0] = 0;
    if (i < N_NODES) {
        int c = i >> 8;
        if (c > 0) rowptr[i + 1] += partials[c - 1];
    }
}

__global__ void init_cursor(const int* __restrict__ rowptr, int* __restrict__ cursor) {
    int i = blockIdx.x * blockDim.x + threadIdx.x;
    if (i < N_NODES) cursor[i] = rowptr[i];
}

__global__ void fill_csr(const int* __restrict__ ei, int* __restrict__ cursor,
                         int* __restrict__ csr_src) {
    int e = blockIdx.x * blockDim.x + threadIdx.x;
    if (e >= ETOT) return;
    int s, d;
    if (e < E_EDGES) { s = ei[e]; d = ei[E_EDGES + e]; }
    else { s = e - E_EDGES; d = s; }
    int pos = atomicAdd(cursor + d, 1);
    csr_src[pos] = s;
}

// ============ layer-1 GEMM: xw1 = x @ W1 (128x128 tile, BK=32), fp16 out ============
#define XP 132   // padded LDS row stride

__global__ __launch_bounds__(256, 2) void gemm1_kernel(const float* __restrict__ x,
                                                       const float* __restrict__ W1,
                                                       __half* __restrict__ xwh) {
    __shared__ float Xs[32][XP];   // Xs[kk][row]
    __shared__ float Ws[32][XP];   // Ws[kk][col]
    int t = threadIdx.x;
    int tx = t & 15, ty = t >> 4;
    int row0 = blockIdx.x * 128;
    float acc[8][8] = {};

    for (int k0 = 0; k0 < IN_CH; k0 += 32) {
#pragma unroll
        for (int p = 0; p < 4; ++p) {
            int idx = t + p * 256;
            int kk = idx >> 5, c4 = idx & 31;
            float4 v = *(const float4*)&W1[(size_t)(k0 + kk) * HH + c4 * 4];
            *(float4*)&Ws[kk][c4 * 4] = v;
        }
#pragma unroll
        for (int p = 0; p < 4; ++p) {
            int idx = t + p * 256;
            int rr = idx >> 3, c4 = idx & 7;
            int row = row0 + rr;
            float4 v = make_float4(0.f, 0.f, 0.f, 0.f);
            if (row < N_NODES) v = *(const float4*)&x[(size_t)row * IN_CH + k0 + c4 * 4];
            Xs[c4 * 4 + 0][rr] = v.x;
            Xs[c4 * 4 + 1][rr] = v.y;
            Xs[c4 * 4 + 2][rr] = v.z;
            Xs[c4 * 4 + 3][rr] = v.w;
        }
        __syncthreads();
#pragma unroll 8
        for (int kk = 0; kk < 32; ++kk) {
            float4 xa0 = *(const float4*)&Xs[kk][ty * 4];
            float4 xa1 = *(const float4*)&Xs[kk][ty * 4 + 64];
            float4 wb0 = *(const float4*)&Ws[kk][tx * 4];
            float4 wb1 = *(const float4*)&Ws[kk][tx * 4 + 64];
            float xa[8] = {xa0.x, xa0.y, xa0.z, xa0.w, xa1.x, xa1.y, xa1.z, xa1.w};
            float wb[8] = {wb0.x, wb0.y, wb0.z, wb0.w, wb1.x, wb1.y, wb1.z, wb1.w};
#pragma unroll
            for (int i = 0; i < 8; ++i)
#pragma unroll
                for (int j = 0; j < 8; ++j)
                    acc[i][j] = fmaf(xa[i], wb[j], acc[i][j]);
        }
        __syncthreads();
    }

#pragma unroll
    for (int i = 0; i < 8; ++i) {
        int row = row0 + ty * 4 + (i < 4 ? i : 60 + i);
        if (row < N_NODES) {
            union { __half2 h2; unsigned u; } c0, c1, c2, c3;
            c0.h2 = __floats2half2_rn(acc[i][0], acc[i][1]);
            c1.h2 = __floats2half2_rn(acc[i][2], acc[i][3]);
            c2.h2 = __floats2half2_rn(acc[i][4], acc[i][5]);
            c3.h2 = __floats2half2_rn(acc[i][6], acc[i][7]);
            *(uint2*)&xwh[(size_t)row * HH + tx * 4]      = make_uint2(c0.u, c1.u);
            *(uint2*)&xwh[(size_t)row * HH + tx * 4 + 64] = make_uint2(c2.u, c3.u);
        }
    }
}

// ================= attention dots from fp16 xw =================
__global__ void att_dots(const __half* __restrict__ xwh,
                         const float* __restrict__ att_s,
                         const float* __restrict__ att_d,
                         float* __restrict__ a1s, float* __restrict__ a1d) {
    int t = threadIdx.x;
    int row = blockIdx.x * 4 + (t >> 6);
    if (row >= N_NODES) return;
    int l = t & 63;
    float2 f = __half22float2(*(const __half2*)&xwh[(size_t)row * HH + 2 * l]);
    float ps = f.x * att_s[2 * l] + f.y * att_s[2 * l + 1];
    float pd = f.x * att_d[2 * l] + f.y * att_d[2 * l + 1];
    for (int off = 8; off; off >>= 1) {
        ps += __shfl_xor(ps, off, 16);
        pd += __shfl_xor(pd, off, 16);
    }
    if ((l & 15) == 0) {
        int h = l >> 4;
        a1s[row * 4 + h] = ps;
        a1d[row * 4 + h] = pd;
    }
}

// ========== layer-1 gather-aggregate, fused denominator, 2-edge ILP ==========
__global__ void gather1(const int* __restrict__ rowptr, const int* __restrict__ csr_src,
                        const float* __restrict__ a1s, const float* __restrict__ a1d,
                        const __half* __restrict__ xwh, float* __restrict__ agg) {
    int t = threadIdx.x;
    int d = blockIdx.x * 4 + (t >> 6);   // one 64-lane wave per node
    if (d >= N_NODES) return;
    int l = t & 63;                       // channels 2l, 2l+1; head = l>>4
    int h = l >> 4;
    float ad = a1d[d * 4 + h];
    int p0 = rowptr[d], p1 = rowptr[d + 1];
    float acc0 = 0.f, acc1 = 0.f, wsum = 0.f;
    int p = p0;
    for (; p + 1 < p1; p += 2) {
        int s0 = csr_src[p], s1 = csr_src[p + 1];
        float v0 = a1s[s0 * 4 + h] + ad; v0 = v0 > 0.f ? v0 : NEG * v0;
        float v1 = a1s[s1 * 4 + h] + ad; v1 = v1 > 0.f ? v1 : NEG * v1;
        float w0 = __expf(v0), w1 = __expf(v1);
        float2 f0 = __half22float2(*(const __half2*)&xwh[(size_t)s0 * HH + 2 * l]);
        float2 f1 = __half22float2(*(const __half2*)&xwh[(size_t)s1 * HH + 2 * l]);
        acc0 = fmaf(w0, f0.x, acc0); acc1 = fmaf(w0, f0.y, acc1);
        acc0 = fmaf(w1, f1.x, acc0); acc1 = fmaf(w1, f1.y, acc1);
        wsum += w0 + w1;
    }
    if (p < p1) {
        int s = csr_src[p];
        float v = a1s[s * 4 + h] + ad; v = v > 0.f ? v : NEG * v;
        float w = __expf(v);
        float2 f = __half22float2(*(const __half2*)&xwh[(size_t)s * HH + 2 * l]);
        acc0 = fmaf(w, f.x, acc0); acc1 = fmaf(w, f.y, acc1);
        wsum += w;
    }
    float r = 1.f / (wsum + 1e-16f);
    *(float2*)&agg[(size_t)d * HH + 2 * l] = make_float2(acc0 * r, acc1 * r);
}

// ====== layer-2 GEMM: h = elu(agg+b1); hw2 = h @ W2 (fp16), + attention dots ======
__global__ void gemm2_kernel(const float* __restrict__ agg1,
                             const float* __restrict__ b1,
                             const float* __restrict__ W2,
                             const float* __restrict__ att_s,
                             const float* __restrict__ att_d,
                             __half* __restrict__ hw2h,
                             float* __restrict__ a2s,
                             float* __restrict__ a2d) {
    __shared__ float Wl[HH * OUT_CH];  // 16 KiB
    __shared__ float hs[8][HH];        // 4 KiB
    int t = threadIdx.x;
    for (int i = t; i < HH * OUT_CH; i += 256) Wl[i] = W2[i];
    __syncthreads();
    int nChunks = (N_NODES + 7) / 8;
    for (int ch = blockIdx.x; ch < nChunks; ch += gridDim.x) {
        int row0 = ch * 8;
        __syncthreads();
        for (int i = t; i < 8 * HH; i += 256) {
            int rr = i >> 7, jj = i & 127;
            int row = row0 + rr;
            if (row < N_NODES) {
                float v = agg1[(size_t)row * HH + jj] + b1[jj];
                hs[rr][jj] = v > 0.f ? v : (__expf(v) - 1.f);   // ELU
            }
        }
        __syncthreads();
        int r = t >> 5, o = t & 31;
        int row = row0 + r;
        if (row < N_NODES) {
            float acc = 0.f;
#pragma unroll 4
            for (int jj = 0; jj < HH; ++jj) acc = fmaf(hs[r][jj], Wl[jj * OUT_CH + o], acc);
            hw2h[(size_t)row * OUT_CH + o] = __float2half_rn(acc);
            float ps = acc * att_s[o], pd = acc * att_d[o];
            for (int off = 16; off; off >>= 1) {
                ps += __shfl_down(ps, off, 32);
                pd += __shfl_down(pd, off, 32);
            }
            if (o == 0) { a2s[row] = ps; a2d[row] = pd; }
        }
    }
}

// ========== layer-2 gather-aggregate, fused denominator, 2-edge ILP ==========
__global__ void gather2(const int* __restrict__ rowptr, const int* __restrict__ csr_src,
                        const float* __restrict__ a2s, const float* __restrict__ a2d,
                        const __half* __restrict__ hw2h, const float* __restrict__ b2,
                        float* __restrict__ out) {
    int t = threadIdx.x;
    int d = blockIdx.x * 8 + (t >> 5);   // 32 lanes per node
    if (d >= N_NODES) return;
    int o = t & 31;
    float ad = a2d[d];
    int p0 = rowptr[d], p1 = rowptr[d + 1];
    float acc = 0.f, wsum = 0.f;
    int p = p0;
    for (; p + 1 < p1; p += 2) {
        int s0 = csr_src[p], s1 = csr_src[p + 1];
        float v0 = a2s[s0] + ad; v0 = v0 > 0.f ? v0 : NEG * v0;
        float v1 = a2s[s1] + ad; v1 = v1 > 0.f ? v1 : NEG * v1;
        float w0 = __expf(v0), w1 = __expf(v1);
        float x0 = __half2float(hw2h[(size_t)s0 * OUT_CH + o]);
        float x1 = __half2float(hw2h[(size_t)s1 * OUT_CH + o]);
        acc = fmaf(w0, x0, acc);
        acc = fmaf(w1, x1, acc);
        wsum += w0 + w1;
    }
    if (p < p1) {
        int s = csr_src[p];
        float v = a2s[s] + ad; v = v > 0.f ? v : NEG * v;
        float w = __expf(v);
        acc = fmaf(w, __half2float(hw2h[(size_t)s * OUT_CH + o]), acc);
        wsum += w;
    }
    out[(size_t)d * OUT_CH + o] = acc / (wsum + 1e-16f) + b2[o];
}

extern "C" void kernel_launch(void* const* d_in, const int* in_sizes, int n_in,
                              void* d_out, int out_size, void* d_ws, size_t ws_size,
                              hipStream_t stream) {
    const float* x   = (const float*)d_in[0];
    const int*   ei  = (const int*)d_in[1];     // int32 (JAX x64 off)
    const float* W1  = (const float*)d_in[2];
    const float* as1 = (const float*)d_in[3];
    const float* ad1 = (const float*)d_in[4];
    const float* b1  = (const float*)d_in[5];
    const float* W2  = (const float*)d_in[6];
    const float* as2 = (const float*)d_in[7];
    const float* ad2 = (const float*)d_in[8];
    const float* b2  = (const float*)d_in[9];
    float* out = (float*)d_out;
    float* ws  = (float*)d_ws;

    // workspace layout (float offsets); peak 10,950,272 floats = 43.8 MB
    __half* xwh   = (__half*)ws;               // 6.4M halves = 3.2M floats; dead after gather1
    __half* hw2h  = (__half*)ws;               // reuse (written by gemm2, after gather1)
    float* agg1   = ws + 3200000;              // 6.4M floats
    float* a1s    = ws + 9600000;              // 200,000 ; a2s reuses
    float* a1d    = ws + 9800000;              // 200,000 ; a2d reuses
    float* a2s    = a1s;
    float* a2d    = a1d;
    int*   deg    = (int*)(ws + 10000000);     // 50,000 (also cursor)
    int*   rowptr = (int*)(ws + 10050000);     // 50,016
    int*   parts  = (int*)(ws + 10100016);     // 256
    int*   csr_src= (int*)(ws + 10100272);     // 850,000 -> end 10,950,272

    // ---- CSR build (graph-only) ----
    init_deg   <<<(N_NODES + 255) / 256, 256, 0, stream>>>(deg);
    count_deg  <<<(E_EDGES + 255) / 256, 256, 0, stream>>>(ei, deg);
    scan_s1    <<<NCHUNK, 256, 0, stream>>>(deg, rowptr, parts);
    scan_s2    <<<1, 256, 0, stream>>>(parts);
    scan_s3    <<<(N_NODES + 255) / 256, 256, 0, stream>>>(rowptr, parts);
    init_cursor<<<(N_NODES + 255) / 256, 256, 0, stream>>>(rowptr, deg);
    fill_csr   <<<(ETOT + 255) / 256, 256, 0, stream>>>(ei, deg, csr_src);

    // ---- layer 1 ----
    gemm1_kernel<<<(N_NODES + 127) / 128, 256, 0, stream>>>(x, W1, xwh);
    att_dots   <<<(N_NODES + 3) / 4, 256, 0, stream>>>(xwh, as1, ad1, a1s, a1d);
    gather1    <<<(N_NODES + 3) / 4, 256, 0, stream>>>(rowptr, csr_src, a1s, a1d, xwh, agg1);

    // ---- layer 2 ----
    gemm2_kernel<<<2048, 256, 0, stream>>>(agg1, b1, W2, as2, ad2, hw2h, a2s, a2d);
    gather2    <<<(N_NODES + 7) / 8, 256, 0, stream>>>(rowptr, csr_src, a2s, a2d, hw2h, b2, out);
}

// Round 7
// 198.135 us; speedup vs baseline: 7.0818x; 1.3190x over previous
//
#include <hip/hip_runtime.h>
#include <hip/hip_fp16.h>

#define N_NODES 50000
#define E_EDGES 800000
#define ETOT (E_EDGES + N_NODES)   // self-loops appended
#define IN_CH 128
#define HH 128                     // HEADS*HID
#define HEADS 4
#define HID 32
#define OUT_CH 32
#define NEG 0.2f

#define GEMM_BLOCKS ((N_NODES + 127) / 128)   // 391
#define FILL_BLOCKS ((ETOT + 1023) / 1024)    // 831
#define XP 132                                // padded LDS row stride

// ===== fused: [blocks 0..390] xw1 = x@W1 + att dots ; [391..] edge-rank atomic pass =====
__global__ __launch_bounds__(256, 2) void gemm1_fused(const float* __restrict__ x,
                                                      const float* __restrict__ W1,
                                                      const float* __restrict__ att_s,
                                                      const float* __restrict__ att_d,
                                                      const int* __restrict__ ei,
                                                      __half* __restrict__ xwh,
                                                      float* __restrict__ a1s,
                                                      float* __restrict__ a1d,
                                                      int* __restrict__ deg,
                                                      int* __restrict__ idx) {
    __shared__ float Xs[32][XP];
    __shared__ float Ws[32][XP];
    int t = threadIdx.x;

    if (blockIdx.x >= GEMM_BLOCKS) {
        // ---------- edge-rank pass: idx[e] = rank of e within its dst group ----------
        int base = (blockIdx.x - GEMM_BLOCKS) * 1024 + t;
#pragma unroll
        for (int q = 0; q < 4; ++q) {
            int e = base + q * 256;
            if (e < ETOT) {
                int d = (e < E_EDGES) ? ei[E_EDGES + e] : e - E_EDGES;
                idx[e] = atomicAdd(deg + d, 1);
            }
        }
        return;
    }

    // ---------- GEMM part: 128x128 tile, BK=32, 8x8 micro-tile ----------
    int tx = t & 15, ty = t >> 4;
    int row0 = blockIdx.x * 128;
    float acc[8][8] = {};

    for (int k0 = 0; k0 < IN_CH; k0 += 32) {
#pragma unroll
        for (int p = 0; p < 4; ++p) {
            int i2 = t + p * 256;
            int kk = i2 >> 5, c4 = i2 & 31;
            float4 v = *(const float4*)&W1[(size_t)(k0 + kk) * HH + c4 * 4];
            *(float4*)&Ws[kk][c4 * 4] = v;
        }
#pragma unroll
        for (int p = 0; p < 4; ++p) {
            int i2 = t + p * 256;
            int rr = i2 >> 3, c4 = i2 & 7;
            int row = row0 + rr;
            float4 v = make_float4(0.f, 0.f, 0.f, 0.f);
            if (row < N_NODES) v = *(const float4*)&x[(size_t)row * IN_CH + k0 + c4 * 4];
            Xs[c4 * 4 + 0][rr] = v.x;
            Xs[c4 * 4 + 1][rr] = v.y;
            Xs[c4 * 4 + 2][rr] = v.z;
            Xs[c4 * 4 + 3][rr] = v.w;
        }
        __syncthreads();
#pragma unroll 8
        for (int kk = 0; kk < 32; ++kk) {
            float4 xa0 = *(const float4*)&Xs[kk][ty * 4];
            float4 xa1 = *(const float4*)&Xs[kk][ty * 4 + 64];
            float4 wb0 = *(const float4*)&Ws[kk][tx * 4];
            float4 wb1 = *(const float4*)&Ws[kk][tx * 4 + 64];
            float xa[8] = {xa0.x, xa0.y, xa0.z, xa0.w, xa1.x, xa1.y, xa1.z, xa1.w};
            float wb[8] = {wb0.x, wb0.y, wb0.z, wb0.w, wb1.x, wb1.y, wb1.z, wb1.w};
#pragma unroll
            for (int i = 0; i < 8; ++i)
#pragma unroll
                for (int j = 0; j < 8; ++j)
                    acc[i][j] = fmaf(xa[i], wb[j], acc[i][j]);
        }
        __syncthreads();
    }

    // att vectors for this thread's 8 columns (cols tx*4+{0..3}, tx*4+64+{0..3})
    float asr[8], adr[8];
#pragma unroll
    for (int j = 0; j < 8; ++j) {
        int col = tx * 4 + (j & 3) + ((j >> 2) << 6);
        asr[j] = att_s[col];
        adr[j] = att_d[col];
    }
    int hA = tx >> 3;   // head of cols tx*4..tx*4+3 (0 or 1); +64 cols are head hA+2

#pragma unroll
    for (int i = 0; i < 8; ++i) {
        int row = row0 + ty * 4 + (i < 4 ? i : 60 + i);
        // store fp16 row chunk
        if (row < N_NODES) {
            union { __half2 h2; unsigned u; } c0, c1, c2, c3;
            c0.h2 = __floats2half2_rn(acc[i][0], acc[i][1]);
            c1.h2 = __floats2half2_rn(acc[i][2], acc[i][3]);
            c2.h2 = __floats2half2_rn(acc[i][4], acc[i][5]);
            c3.h2 = __floats2half2_rn(acc[i][6], acc[i][7]);
            *(uint2*)&xwh[(size_t)row * HH + tx * 4]      = make_uint2(c0.u, c1.u);
            *(uint2*)&xwh[(size_t)row * HH + tx * 4 + 64] = make_uint2(c2.u, c3.u);
        }
        // per-head attention dots: heads hA (cols 0..3) and hA+2 (cols 4..7)
        float psA = 0.f, pdA = 0.f, psB = 0.f, pdB = 0.f;
#pragma unroll
        for (int j = 0; j < 4; ++j) {
            psA = fmaf(acc[i][j], asr[j], psA);
            pdA = fmaf(acc[i][j], adr[j], pdA);
            psB = fmaf(acc[i][j + 4], asr[j + 4], psB);
            pdB = fmaf(acc[i][j + 4], adr[j + 4], pdB);
        }
        // reduce across the 8 tx-lanes sharing each head (xor 1,2,4 within 16-lane group)
#pragma unroll
        for (int off = 1; off < 8; off <<= 1) {
            psA += __shfl_xor(psA, off, 16);
            pdA += __shfl_xor(pdA, off, 16);
            psB += __shfl_xor(psB, off, 16);
            pdB += __shfl_xor(pdB, off, 16);
        }
        if ((tx & 7) == 0 && row < N_NODES) {
            a1s[row * 4 + hA]     = psA;
            a1d[row * 4 + hA]     = pdA;
            a1s[row * 4 + hA + 2] = psB;
            a1d[row * 4 + hA + 2] = pdB;
        }
    }
}

// ================= scan (rowptr from deg) =================
__device__ __forceinline__ int block_incl_scan(int v, int t) {
    for (int off = 1; off < 64; off <<= 1) {
        int n = __shfl_up(v, off, 64);
        if ((t & 63) >= off) v += n;
    }
    __shared__ int wsum[4];
    if ((t & 63) == 63) wsum[t >> 6] = v;
    __syncthreads();
    int w = t >> 6;
    if (w > 0) {
        int add = 0;
        for (int k = 0; k < w; ++k) add += wsum[k];
        v += add;
    }
    __syncthreads();
    return v;
}

#define NCHUNK ((N_NODES + 255) / 256)   // 196

__global__ void scan_s1(const int* __restrict__ deg, int* __restrict__ rowptr,
                        int* __restrict__ partials) {
    int t = threadIdx.x;
    int i = blockIdx.x * 256 + t;
    int v = (i < N_NODES) ? deg[i] : 0;
    int s = block_incl_scan(v, t);
    if (i < N_NODES) rowptr[i + 1] = s;
    if (t == 255) partials[blockIdx.x] = s;
}

__global__ void scan_s2(int* __restrict__ partials) {
    int t = threadIdx.x;
    int v = (t < NCHUNK) ? partials[t] : 0;
    int s = block_incl_scan(v, t);
    if (t < NCHUNK) partials[t] = s;
}

__global__ void scan_s3(int* __restrict__ rowptr, const int* __restrict__ partials) {
    int i = blockIdx.x * blockDim.x + threadIdx.x;
    if (i == 0) rowptr[0] = 0;
    if (i < N_NODES) {
        int c = i >> 8;
        if (c > 0) rowptr[i + 1] += partials[c - 1];
    }
}

// ================= place: csr_src[rowptr[d]+idx[e]] = s (no atomics) =================
__global__ void place_csr(const int* __restrict__ ei, const int* __restrict__ idx,
                          const int* __restrict__ rowptr, int* __restrict__ csr_src) {
    int e = blockIdx.x * blockDim.x + threadIdx.x;
    if (e >= ETOT) return;
    int s, d;
    if (e < E_EDGES) { s = ei[e]; d = ei[E_EDGES + e]; }
    else { s = e - E_EDGES; d = s; }
    csr_src[rowptr[d] + idx[e]] = s;
}

// ========== layer-1 gather-aggregate, fused denominator, 2-edge ILP ==========
__global__ void gather1(const int* __restrict__ rowptr, const int* __restrict__ csr_src,
                        const float* __restrict__ a1s, const float* __restrict__ a1d,
                        const __half* __restrict__ xwh, float* __restrict__ agg) {
    int t = threadIdx.x;
    int d = blockIdx.x * 4 + (t >> 6);   // one 64-lane wave per node
    if (d >= N_NODES) return;
    int l = t & 63;                       // channels 2l, 2l+1; head = l>>4
    int h = l >> 4;
    float ad = a1d[d * 4 + h];
    int p0 = rowptr[d], p1 = rowptr[d + 1];
    float acc0 = 0.f, acc1 = 0.f, wsum = 0.f;
    int p = p0;
    for (; p + 1 < p1; p += 2) {
        int s0 = csr_src[p], s1 = csr_src[p + 1];
        float v0 = a1s[s0 * 4 + h] + ad; v0 = v0 > 0.f ? v0 : NEG * v0;
        float v1 = a1s[s1 * 4 + h] + ad; v1 = v1 > 0.f ? v1 : NEG * v1;
        float w0 = __expf(v0), w1 = __expf(v1);
        float2 f0 = __half22float2(*(const __half2*)&xwh[(size_t)s0 * HH + 2 * l]);
        float2 f1 = __half22float2(*(const __half2*)&xwh[(size_t)s1 * HH + 2 * l]);
        acc0 = fmaf(w0, f0.x, acc0); acc1 = fmaf(w0, f0.y, acc1);
        acc0 = fmaf(w1, f1.x, acc0); acc1 = fmaf(w1, f1.y, acc1);
        wsum += w0 + w1;
    }
    if (p < p1) {
        int s = csr_src[p];
        float v = a1s[s * 4 + h] + ad; v = v > 0.f ? v : NEG * v;
        float w = __expf(v);
        float2 f = __half22float2(*(const __half2*)&xwh[(size_t)s * HH + 2 * l]);
        acc0 = fmaf(w, f.x, acc0); acc1 = fmaf(w, f.y, acc1);
        wsum += w;
    }
    float r = 1.f / (wsum + 1e-16f);
    *(float2*)&agg[(size_t)d * HH + 2 * l] = make_float2(acc0 * r, acc1 * r);
}

// ====== layer-2 GEMM: h = elu(agg+b1); hw2 = h @ W2 (fp16), + attention dots ======
__global__ void gemm2_kernel(const float* __restrict__ agg1,
                             const float* __restrict__ b1,
                             const float* __restrict__ W2,
                             const float* __restrict__ att_s,
                             const float* __restrict__ att_d,
                             __half* __restrict__ hw2h,
                             float* __restrict__ a2s,
                             float* __restrict__ a2d) {
    __shared__ float Wl[HH * OUT_CH];  // 16 KiB
    __shared__ float hs[8][HH];        // 4 KiB
    int t = threadIdx.x;
    for (int i = t; i < HH * OUT_CH; i += 256) Wl[i] = W2[i];
    __syncthreads();
    int nChunks = (N_NODES + 7) / 8;
    for (int ch = blockIdx.x; ch < nChunks; ch += gridDim.x) {
        int row0 = ch * 8;
        __syncthreads();
        for (int i = t; i < 8 * HH; i += 256) {
            int rr = i >> 7, jj = i & 127;
            int row = row0 + rr;
            if (row < N_NODES) {
                float v = agg1[(size_t)row * HH + jj] + b1[jj];
                hs[rr][jj] = v > 0.f ? v : (__expf(v) - 1.f);   // ELU
            }
        }
        __syncthreads();
        int r = t >> 5, o = t & 31;
        int row = row0 + r;
        if (row < N_NODES) {
            float acc = 0.f;
#pragma unroll 4
            for (int jj = 0; jj < HH; ++jj) acc = fmaf(hs[r][jj], Wl[jj * OUT_CH + o], acc);
            hw2h[(size_t)row * OUT_CH + o] = __float2half_rn(acc);
            float ps = acc * att_s[o], pd = acc * att_d[o];
            for (int off = 16; off; off >>= 1) {
                ps += __shfl_down(ps, off, 32);
                pd += __shfl_down(pd, off, 32);
            }
            if (o == 0) { a2s[row] = ps; a2d[row] = pd; }
        }
    }
}

// ========== layer-2 gather-aggregate, fused denominator, 2-edge ILP ==========
__global__ void gather2(const int* __restrict__ rowptr, const int* __restrict__ csr_src,
                        const float* __restrict__ a2s, const float* __restrict__ a2d,
                        const __half* __restrict__ hw2h, const float* __restrict__ b2,
                        float* __restrict__ out) {
    int t = threadIdx.x;
    int d = blockIdx.x * 8 + (t >> 5);   // 32 lanes per node
    if (d >= N_NODES) return;
    int o = t & 31;
    float ad = a2d[d];
    int p0 = rowptr[d], p1 = rowptr[d + 1];
    float acc = 0.f, wsum = 0.f;
    int p = p0;
    for (; p + 1 < p1; p += 2) {
        int s0 = csr_src[p], s1 = csr_src[p + 1];
        float v0 = a2s[s0] + ad; v0 = v0 > 0.f ? v0 : NEG * v0;
        float v1 = a2s[s1] + ad; v1 = v1 > 0.f ? v1 : NEG * v1;
        float w0 = __expf(v0), w1 = __expf(v1);
        float x0 = __half2float(hw2h[(size_t)s0 * OUT_CH + o]);
        float x1 = __half2float(hw2h[(size_t)s1 * OUT_CH + o]);
        acc = fmaf(w0, x0, acc);
        acc = fmaf(w1, x1, acc);
        wsum += w0 + w1;
    }
    if (p < p1) {
        int s = csr_src[p];
        float v = a2s[s] + ad; v = v > 0.f ? v : NEG * v;
        float w = __expf(v);
        acc = fmaf(w, __half2float(hw2h[(size_t)s * OUT_CH + o]), acc);
        wsum += w;
    }
    out[(size_t)d * OUT_CH + o] = acc / (wsum + 1e-16f) + b2[o];
}

extern "C" void kernel_launch(void* const* d_in, const int* in_sizes, int n_in,
                              void* d_out, int out_size, void* d_ws, size_t ws_size,
                              hipStream_t stream) {
    const float* x   = (const float*)d_in[0];
    const int*   ei  = (const int*)d_in[1];     // int32 (JAX x64 off)
    const float* W1  = (const float*)d_in[2];
    const float* as1 = (const float*)d_in[3];
    const float* ad1 = (const float*)d_in[4];
    const float* b1  = (const float*)d_in[5];
    const float* W2  = (const float*)d_in[6];
    const float* as2 = (const float*)d_in[7];
    const float* ad2 = (const float*)d_in[8];
    const float* b2  = (const float*)d_in[9];
    float* out = (float*)d_out;
    float* ws  = (float*)d_ws;

    // workspace layout (float offsets); peak ~11.8M floats = 47.2 MB
    __half* xwh   = (__half*)ws;               // 6.4M halves = 3.2M floats; dead after gather1
    __half* hw2h  = (__half*)ws;               // reuse (written by gemm2 after gather1)
    float* agg1   = ws + 3200000;              // 6.4M floats
    float* a1s    = ws + 9600000;              // 200,000 ; a2s reuses
    float* a1d    = ws + 9800000;              // 200,000 ; a2d reuses
    float* a2s    = a1s;
    float* a2d    = a1d;
    int*   deg    = (int*)(ws + 10000000);     // 50,000
    int*   rowptr = (int*)(ws + 10050000);     // 50,016
    int*   parts  = (int*)(ws + 10100016);     // 256
    int*   csr_src= (int*)(ws + 10100272);     // 850,000
    int*   idx    = (int*)(ws + 10950272);     // 850,000 -> end 11,800,272

    hipMemsetAsync(deg, 0, (size_t)N_NODES * sizeof(int), stream);

    // fused: gemm1 (+att dots) on blocks [0,391), edge-rank atomics on [391, 1222)
    gemm1_fused<<<GEMM_BLOCKS + FILL_BLOCKS, 256, 0, stream>>>(
        x, W1, as1, ad1, ei, xwh, a1s, a1d, deg, idx);

    scan_s1  <<<NCHUNK, 256, 0, stream>>>(deg, rowptr, parts);
    scan_s2  <<<1, 256, 0, stream>>>(parts);
    scan_s3  <<<(N_NODES + 255) / 256, 256, 0, stream>>>(rowptr, parts);
    place_csr<<<(ETOT + 255) / 256, 256, 0, stream>>>(ei, idx, rowptr, csr_src);

    gather1  <<<(N_NODES + 3) / 4, 256, 0, stream>>>(rowptr, csr_src, a1s, a1d, xwh, agg1);

    gemm2_kernel<<<2048, 256, 0, stream>>>(agg1, b1, W2, as2, ad2, hw2h, a2s, a2d);
    gather2  <<<(N_NODES + 7) / 8, 256, 0, stream>>>(rowptr, csr_src, a2s, a2d, hw2h, b2, out);
}